// Round 2
// baseline (1119.465 us; speedup 1.0000x reference)
//
#include <hip/hip_runtime.h>
#include <math.h>

#define N_ATOMS 50000
#define P_PAIRS 1600000
#define TA 16
#define CAP_MAX 96
#define CSTRIDE 16   // cnt padded to one counter per 64B line

__device__ __forceinline__ float gelu_exact(float x) {
    return 0.5f * x * (1.0f + erff(x * 0.70710678118654752440f));
}

// Invert pair->atom index: bucket[idx][pos] = pair id.
__global__ __launch_bounds__(256) void build_buckets(
    const int* __restrict__ idx_j,
    int* __restrict__ cnt,
    int* __restrict__ bucket,
    int cap)
{
    int p = blockIdx.x * 256 + threadIdx.x;
    int idx = idx_j[p];
    int pos = atomicAdd(cnt + idx * CSTRIDE, 1);
    if (pos < cap) bucket[(size_t)idx * cap + pos] = p;
}

// LDS pool layout (floats), by liveness:
//   embT   [0 .. 2047]      emb^T [a][atom]          (dead after MLP1 k-loop)
//   gs     [2048 .. 2303]   [atom][g]                (dead after mapped pass)
//   gv     [2304 .. 3071]   [atom][d*16+g]           (dead after avf)
//   q      [3072 .. 3087]   [atom]                   (dead after MLP1 k-loop)
//   U      [3088 .. 7183]   [atom][256 gh_local]     (per-phase, dead after avf)
//   mapped [3088 .. 5135]   [f][atom]                (dead after MLP1 k-loop)
//   vec    [5136 .. 5647]   [h][atom]                (dead after MLP1 k-loop)
//   h1T    [0 .. 4095]      [o][atom]  (written after barrier post-MLP1-reads)
//   h2T    [4096 .. 6143]   [o][atom]
#define POOL_FLOATS 7184

__global__ __launch_bounds__(256, 5) void fused_atom_kernel(
    const float* __restrict__ emb,
    const float* __restrict__ qch,
    const int* __restrict__ cnt,
    const int* __restrict__ bucket,
    const float* __restrict__ gs,
    const float* __restrict__ gv,
    const float* __restrict__ agh,   // (128,16,32) -> [a*512 + g*32 + h]
    const float* __restrict__ W_gf,  // (16,128)
    const float* __restrict__ W1, const float* __restrict__ b1,   // (320,256)
    const float* __restrict__ W2, const float* __restrict__ b2,   // (256,128)
    const float* __restrict__ W3, const float* __restrict__ b3,   // (128,130)
    int cap,
    float* __restrict__ out)
{
    __shared__ __align__(16) float sp[POOL_FLOATS];

    const int tid = threadIdx.x;
    const int n0 = blockIdx.x * TA;

    float* s_embT = sp;           // [128][16]
    float* s_gs   = sp + 2048;    // [16][16]
    float* s_gv   = sp + 2304;    // [16][48]
    float* s_q    = sp + 3072;    // [16]
    float* s_U    = sp + 3088;    // [16][256]
    float* s_map  = sp + 3088;    // [128][16]
    float* s_vec  = sp + 5136;    // [32][16]
    float* s_h1T  = sp;           // [256][16]
    float* s_h2T  = sp + 4096;    // [128][16]

    // ---- stage emb (transposed into LDS) ----
    #pragma unroll
    for (int i = 0; i < 2; i++) {
        int ii = tid + i * 256;           // float4 index, 512 total
        int atom = ii >> 5;               // 32 float4 per atom row
        int a4 = (ii & 31) * 4;
        float4 v = *(const float4*)(emb + (size_t)(n0 + atom) * 128 + a4);
        s_embT[(a4 + 0) * 16 + atom] = v.x;
        s_embT[(a4 + 1) * 16 + atom] = v.y;
        s_embT[(a4 + 2) * 16 + atom] = v.z;
        s_embT[(a4 + 3) * 16 + atom] = v.w;
    }

    // ---- gather per-atom gs/gv sums from pair buckets ----
    {
        const int g = tid >> 4;           // atom within tile
        const int l = tid & 15;           // 16 lanes cover 64 components
        const int n = n0 + g;
        int c = cnt[n * CSTRIDE]; if (c > cap) c = cap;
        const int* brow = bucket + (size_t)n * cap;
        const float* base; int stride;
        if (l < 4) { base = gs + l * 4;       stride = 16; }
        else       { base = gv + (l - 4) * 4; stride = 48; }
        float4 a = make_float4(0.f, 0.f, 0.f, 0.f);
        int i = 0;
        for (; i + 4 <= c; i += 4) {
            int p0 = brow[i + 0], p1 = brow[i + 1];
            int p2 = brow[i + 2], p3 = brow[i + 3];
            float4 v0 = *(const float4*)(base + (size_t)p0 * stride);
            float4 v1 = *(const float4*)(base + (size_t)p1 * stride);
            float4 v2 = *(const float4*)(base + (size_t)p2 * stride);
            float4 v3 = *(const float4*)(base + (size_t)p3 * stride);
            a.x += (v0.x + v1.x) + (v2.x + v3.x);
            a.y += (v0.y + v1.y) + (v2.y + v3.y);
            a.z += (v0.z + v1.z) + (v2.z + v3.z);
            a.w += (v0.w + v1.w) + (v2.w + v3.w);
        }
        for (; i < c; i++) {
            int p0 = brow[i];
            float4 v0 = *(const float4*)(base + (size_t)p0 * stride);
            a.x += v0.x; a.y += v0.y; a.z += v0.z; a.w += v0.w;
        }
        if (l < 4) *(float4*)(s_gs + g * 16 + l * 4)       = a;
        else       *(float4*)(s_gv + g * 48 + (l - 4) * 4) = a;
    }
    if (tid < 16) s_q[tid] = qch[n0 + tid];
    __syncthreads();

    // ---- U in two gh-halves; avf accumulates across phases in registers ----
    float av[2][3];
    #pragma unroll
    for (int it = 0; it < 2; it++) { av[it][0] = 0.f; av[it][1] = 0.f; av[it][2] = 0.f; }

    #pragma unroll
    for (int ph = 0; ph < 2; ph++) {
        // U_half[atom][ghl] = sum_a emb[atom][a] * agh[a][ph*256 + ghl]
        {
            const int ghl4 = (tid & 63) * 4;    // 64 threads cover 256 gh
            const int quad = tid >> 6;          // atoms quad*4 .. +3
            float u[16];
            #pragma unroll
            for (int i = 0; i < 16; i++) u[i] = 0.f;
            #pragma unroll 4
            for (int a = 0; a < 128; a++) {
                float4 w = *(const float4*)(agh + a * 512 + ph * 256 + ghl4);
                float4 e = *(const float4*)(s_embT + a * 16 + quad * 4);
                float wv[4] = {w.x, w.y, w.z, w.w};
                float ev[4] = {e.x, e.y, e.z, e.w};
                #pragma unroll
                for (int j = 0; j < 4; j++)
                    #pragma unroll
                    for (int m = 0; m < 4; m++)
                        u[j * 4 + m] += wv[j] * ev[m];
            }
            #pragma unroll
            for (int m = 0; m < 4; m++) {
                int atom = quad * 4 + m;
                float4 v = {u[0 * 4 + m], u[1 * 4 + m], u[2 * 4 + m], u[3 * 4 + m]};
                *(float4*)(s_U + atom * 256 + ghl4) = v;
            }
        }
        __syncthreads();

        // avf partial: g in [ph*8, ph*8+8)
        #pragma unroll
        for (int it = 0; it < 2; it++) {
            int i = tid + it * 256;
            int atom = i >> 5, h = i & 31;
            #pragma unroll
            for (int g = 0; g < 8; g++) {
                float uv = s_U[atom * 256 + g * 32 + h];
                int gg = ph * 8 + g;
                av[it][0] += uv * s_gv[atom * 48 + gg];
                av[it][1] += uv * s_gv[atom * 48 + 16 + gg];
                av[it][2] += uv * s_gv[atom * 48 + 32 + gg];
            }
        }
        __syncthreads();
    }

    // ---- write vec (safe_norm) and mapped = GS_sum @ W_gf ----
    #pragma unroll
    for (int it = 0; it < 2; it++) {
        int i = tid + it * 256;
        int atom = i >> 5, h = i & 31;
        float sq = av[it][0] * av[it][0] + av[it][1] * av[it][1] + av[it][2] * av[it][2];
        s_vec[h * 16 + atom] = (sq > 0.f) ? sqrtf(sq) : 0.f;
    }
    {
        const int f = tid & 127;
        const int half = tid >> 7;
        float mp[8];
        #pragma unroll
        for (int a = 0; a < 8; a++) mp[a] = 0.f;
        #pragma unroll
        for (int g = 0; g < 16; g++) {
            float w = W_gf[g * 128 + f];
            #pragma unroll
            for (int a = 0; a < 8; a++)
                mp[a] += s_gs[(half * 8 + a) * 16 + g] * w;
        }
        #pragma unroll
        for (int a = 0; a < 8; a++)
            s_map[f * 16 + half * 8 + a] = mp[a];
    }
    __syncthreads();

    // ---- MLP layer 1: h1 = gelu(msg @ W1 + b1); msg rows built on the fly ----
    {
        const int o4 = (tid & 63) * 4;      // 4 consecutive output cols
        const int q4 = (tid >> 6) * 4;      // 4 consecutive atoms
        float acc1[16];
        #pragma unroll
        for (int i = 0; i < 16; i++) acc1[i] = 0.f;
        float qv[4] = {s_q[q4 + 0], s_q[q4 + 1], s_q[q4 + 2], s_q[q4 + 3]};

        // rows [0,128): emb*mapped with W1[f];  rows [160,288): q*mapped with W1[160+f]
        #pragma unroll 2
        for (int f = 0; f < 128; f++) {
            float4 wa = *(const float4*)(W1 + f * 256 + o4);
            float4 wb = *(const float4*)(W1 + (160 + f) * 256 + o4);
            float4 mm = *(const float4*)(s_map + f * 16 + q4);
            float4 ee = *(const float4*)(s_embT + f * 16 + q4);
            float wav[4] = {wa.x, wa.y, wa.z, wa.w};
            float wbv[4] = {wb.x, wb.y, wb.z, wb.w};
            float rm[4]  = {mm.x * ee.x, mm.y * ee.y, mm.z * ee.z, mm.w * ee.w};
            float rq[4]  = {mm.x * qv[0], mm.y * qv[1], mm.z * qv[2], mm.w * qv[3]};
            #pragma unroll
            for (int j = 0; j < 4; j++)
                #pragma unroll
                for (int m = 0; m < 4; m++)
                    acc1[j * 4 + m] += wav[j] * rm[m] + wbv[j] * rq[m];
        }
        // rows [128,160): vec_emb.  rows [288,320) are zero -> skipped.
        #pragma unroll 4
        for (int h = 0; h < 32; h++) {
            float4 w  = *(const float4*)(W1 + (128 + h) * 256 + o4);
            float4 vv = *(const float4*)(s_vec + h * 16 + q4);
            float wv[4] = {w.x, w.y, w.z, w.w};
            float mv[4] = {vv.x, vv.y, vv.z, vv.w};
            #pragma unroll
            for (int j = 0; j < 4; j++)
                #pragma unroll
                for (int m = 0; m < 4; m++)
                    acc1[j * 4 + m] += wv[j] * mv[m];
        }
        __syncthreads();   // embT/map/vec/q reads done before h1T overwrites pool
        #pragma unroll
        for (int j = 0; j < 4; j++) {
            int o = o4 + j;
            float bb = b1[o];
            float4 v;
            v.x = gelu_exact(acc1[j * 4 + 0] + bb);
            v.y = gelu_exact(acc1[j * 4 + 1] + bb);
            v.z = gelu_exact(acc1[j * 4 + 2] + bb);
            v.w = gelu_exact(acc1[j * 4 + 3] + bb);
            *(float4*)(s_h1T + o * 16 + q4) = v;
        }
    }
    __syncthreads();

    // ---- MLP layer 2: h2 = gelu(h1 @ W2 + b2), 256 -> 128 ----
    {
        const int o4 = (tid & 31) * 4;
        const int a2 = (tid >> 5) * 2;
        float acc2[8];
        #pragma unroll
        for (int i = 0; i < 8; i++) acc2[i] = 0.f;
        #pragma unroll 4
        for (int k = 0; k < 256; k++) {
            float4 w  = *(const float4*)(W2 + k * 128 + o4);
            float2 hh = *(const float2*)(s_h1T + k * 16 + a2);
            float wv[4] = {w.x, w.y, w.z, w.w};
            float hv[2] = {hh.x, hh.y};
            #pragma unroll
            for (int j = 0; j < 4; j++)
                #pragma unroll
                for (int m = 0; m < 2; m++)
                    acc2[j * 2 + m] += wv[j] * hv[m];
        }
        // h2T region (pool[4096..6143]) is disjoint from h1T (pool[0..4095]) -> no barrier
        #pragma unroll
        for (int j = 0; j < 4; j++) {
            int o = o4 + j;
            float bb = b2[o];
            float2 v;
            v.x = gelu_exact(acc2[j * 2 + 0] + bb);
            v.y = gelu_exact(acc2[j * 2 + 1] + bb);
            *(float2*)(s_h2T + o * 16 + a2) = v;
        }
    }
    __syncthreads();

    // ---- MLP layer 3: out = h2 @ W3 + b3, 128 -> 130 ----
    {
        const int o4 = (tid & 31) * 4 + 2;   // cols 2..129 (delta_a)
        const int a2 = (tid >> 5) * 2;
        float acc3[8];
        #pragma unroll
        for (int i = 0; i < 8; i++) acc3[i] = 0.f;
        #pragma unroll 4
        for (int k = 0; k < 128; k++) {
            const float* wp = W3 + k * 130 + o4;     // even element offset -> 8B aligned
            float2 wa = *(const float2*)(wp);
            float2 wb = *(const float2*)(wp + 2);
            float2 hh = *(const float2*)(s_h2T + k * 16 + a2);
            float wv[4] = {wa.x, wa.y, wb.x, wb.y};
            float hv[2] = {hh.x, hh.y};
            #pragma unroll
            for (int j = 0; j < 4; j++)
                #pragma unroll
                for (int m = 0; m < 2; m++)
                    acc3[j * 2 + m] += wv[j] * hv[m];
        }
        #pragma unroll
        for (int m = 0; m < 2; m++) {
            int n = n0 + a2 + m;
            float4 v;
            v.x = acc3[0 * 2 + m] + b3[o4 + 0];
            v.y = acc3[1 * 2 + m] + b3[o4 + 1];
            v.z = acc3[2 * 2 + m] + b3[o4 + 2];
            v.w = acc3[3 * 2 + m] + b3[o4 + 3];
            *(float4*)(out + (size_t)n * 128 + (o4 - 2)) = v;
        }

        // delta_q (col 0) and f (col 1)
        if (tid < 32) {
            int atom = tid >> 1, col = tid & 1;
            float s = 0.f;
            #pragma unroll 4
            for (int k = 0; k < 128; k++)
                s += s_h2T[k * 16 + atom] * W3[k * 130 + col];
            s += b3[col];
            out[(size_t)N_ATOMS * 128 + (size_t)col * N_ATOMS + (n0 + atom)] = s;
        }
    }
}

extern "C" void kernel_launch(void* const* d_in, const int* in_sizes, int n_in,
                              void* d_out, int out_size, void* d_ws, size_t ws_size,
                              hipStream_t stream)
{
    const float* emb  = (const float*)d_in[0];
    const float* qch  = (const float*)d_in[1];
    const int*   pidx = (const int*)d_in[2];
    const float* gs   = (const float*)d_in[3];
    const float* gv   = (const float*)d_in[4];
    const float* agh  = (const float*)d_in[5];
    const float* W_gf = (const float*)d_in[6];
    const float* W1   = (const float*)d_in[7];
    const float* b1   = (const float*)d_in[8];
    const float* W2   = (const float*)d_in[9];
    const float* b2   = (const float*)d_in[10];
    const float* W3   = (const float*)d_in[11];
    const float* b3   = (const float*)d_in[12];

    // workspace: cnt (N * CSTRIDE int, 64B-padded counters) | bucket (N * cap int)
    int* cnt = (int*)d_ws;
    const size_t cnt_bytes = (size_t)N_ATOMS * CSTRIDE * sizeof(int);   // 3.2 MB
    int* bucket = (int*)((char*)d_ws + cnt_bytes);
    size_t avail = (ws_size > cnt_bytes) ? (ws_size - cnt_bytes) : 0;
    size_t cap_fit = avail / ((size_t)N_ATOMS * sizeof(int));
    int cap = cap_fit > CAP_MAX ? CAP_MAX : (int)cap_fit;

    hipMemsetAsync(cnt, 0, cnt_bytes, stream);

    build_buckets<<<P_PAIRS / 256, 256, 0, stream>>>(
        pidx + P_PAIRS, cnt, bucket, cap);

    fused_atom_kernel<<<N_ATOMS / TA, 256, 0, stream>>>(
        emb, qch, cnt, bucket, gs, gv, agh, W_gf,
        W1, b1, W2, b2, W3, b3, cap, (float*)d_out);
}